// Round 1
// baseline (48.947 us; speedup 1.0000x reference)
//
#include <hip/hip_runtime.h>
#include <stdint.h>

#define HT 56
#define WD 56
#define CH 16
#define FT 16
#define KK 144          // 3*3*16 patch size
#define PPB 16          // pixels per block
#define THREADS 256

// Phase 1: each wave rank-sorts 4 pixels' (t, k) keys into LDS.
// Phase 2: each thread = (pixel, feature); serial scan over sorted entries.
__global__ __launch_bounds__(THREADS) void spiking_conv2d_kernel(
    const float* __restrict__ tj,        // [B,56,56,16]
    const float* __restrict__ kern,      // [3,3,16,16] -> flat [144*16]
    const float* __restrict__ threshold, // [16]
    const float* __restrict__ alpha,     // [16]
    float* __restrict__ out,             // [B,56,56,16]
    int npix)
{
    __shared__ float    sJ[KK * FT];          // 9216 B
    __shared__ float    sThr[FT];
    __shared__ float    sAl[FT];
    __shared__ uint64_t sKey[4][KK];          // per-wave unsorted keys, 4608 B
    __shared__ uint64_t sSorted[PPB][KK + 1]; // +1 = FAR_FUTURE sentinel, 18560 B

    const int tid  = threadIdx.x;
    const int wave = tid >> 6;
    const int lane = tid & 63;

    // stage weights / params into LDS
    for (int i = tid; i < KK * FT; i += THREADS) sJ[i] = kern[i];
    if (tid < FT) { sThr[tid] = threshold[tid]; sAl[tid] = alpha[tid]; }

    // ---------------- phase 1: load + stable rank-sort (one wave per pixel) ----
    for (int i = 0; i < 4; ++i) {
        const int p = wave * 4 + i;
        const int n = blockIdx.x * PPB + p;
        if (n < npix) {
            const int b   = n / (HT * WD);
            const int rem = n - b * (HT * WD);
            const int y   = rem / WD;
            const int x   = rem - y * WD;

            uint64_t key[3] = {0ull, 0ull, 0ull};
            int      rank[3] = {0, 0, 0};
            #pragma unroll
            for (int e = 0; e < 3; ++e) {
                const int k = lane + 64 * e;
                if (k < KK) {
                    const int tap = k >> 4;       // di*3+dj
                    const int c   = k & 15;
                    const int di  = tap / 3;
                    const int dj  = tap - 3 * di;
                    const int yy  = y + di - 1;   // 'same' pad
                    const int xx  = x + dj - 1;
                    float t = 0.0f;               // T_MIN pad value
                    if ((unsigned)yy < (unsigned)HT && (unsigned)xx < (unsigned)WD)
                        t = tj[(((b * HT) + yy) * WD + xx) * CH + c];
                    // key = (bits(t), k): t >= 0 so unsigned order == float order;
                    // low 32 bits give the stable tie-break jnp.argsort uses.
                    key[e] = ((uint64_t)__float_as_uint(t) << 32) | (uint32_t)k;
                    sKey[wave][k] = key[e];
                }
            }
            // wave-synchronous: LDS writes above visible to this wave's reads below
            #pragma unroll 4
            for (int j = 0; j < KK; ++j) {
                const uint64_t kj = sKey[wave][j];   // broadcast read
                rank[0] += (kj < key[0]);
                rank[1] += (kj < key[1]);
                rank[2] += (kj < key[2]);
            }
            #pragma unroll
            for (int e = 0; e < 3; ++e) {
                const int k = lane + 64 * e;
                if (k < KK) sSorted[p][rank[e]] = key[e];
            }
            if (lane == 0)   // FAR_FUTURE sentinel so scan needs no tail branch
                sSorted[p][KK] = ((uint64_t)__float_as_uint(1.0e6f) << 32);
        }
    }
    __syncthreads();

    // ---------------- phase 2: scan, one thread per (pixel, feature) -----------
    {
        const int p = tid >> 4;
        const int f = tid & 15;
        const int n = blockIdx.x * PPB + p;
        if (n < npix) {
            const float thr = sThr[f];
            const float al  = sAl[f];
            float num = 0.0f, den = 0.0f;
            float selN = 0.0f, selD = 1.0f;
            bool  found = false;
            uint64_t ecur = sSorted[p][0];
            #pragma unroll 4
            for (int k = 0; k < KK; ++k) {
                const float t  = __uint_as_float((uint32_t)(ecur >> 32));
                const int   kj = (int)(uint32_t)ecur;
                const uint64_t enext = sSorted[p][k + 1];
                const float tn = __uint_as_float((uint32_t)(enext >> 32));
                const float w  = sJ[kj * FT + f];
                num = fmaf(w, t, num);     // cumsum(J*t)
                den += w;                  // cumsum(J)
                const float numt = num + thr;          // + alpha*T_MIN_PREV (=0)
                const float dena = den + al;
                // valid = (numt/dena < tn) && (dena > 0)  -- division-free form
                const bool valid = (dena > 0.0f) && (numt < tn * dena);
                const bool take  = (!found) && (valid || (k == 0)); // argmax fallback=0
                if (take) { selN = numt; selD = dena; }
                found = found || valid;
                ecur = enext;
            }
            const float ti = selN / selD;
            out[n * FT + f] = (ti < 1.0f) ? ti : 1.0f;   // clamp to T_MAX
        }
    }
}

extern "C" void kernel_launch(void* const* d_in, const int* in_sizes, int n_in,
                              void* d_out, int out_size, void* d_ws, size_t ws_size,
                              hipStream_t stream) {
    const float* tj    = (const float*)d_in[0];
    const float* kern  = (const float*)d_in[1];
    const float* thr   = (const float*)d_in[2];
    const float* alpha = (const float*)d_in[3];
    float*       out   = (float*)d_out;

    const int npix   = in_sizes[0] / CH;                 // B*H*W = 12544
    const int blocks = (npix + PPB - 1) / PPB;           // 784
    spiking_conv2d_kernel<<<blocks, THREADS, 0, stream>>>(tj, kern, thr, alpha, out, npix);
}

// Round 2
// 38.284 us; speedup vs baseline: 1.2785x; 1.2785x over previous
//
#include <hip/hip_runtime.h>
#include <stdint.h>

#define HT 56
#define WD 56
#define CH 16
#define FT 16
#define KK 144          // 3*3*16 patch size
#define WAVES 4         // waves per block = pixels per block
#define THREADS 256
#define CHUNK 36        // KK / 4 position-chunks in phase 2

// One wave = one output pixel.
// Phase 1: rank-sort the 144 (t,k) keys (3 keys/lane, u64 compares, in-place LDS).
// Phase 2: 64 lanes = 16 features x 4 chunks of 36 sorted positions;
//          pass A partial sums -> shfl scan -> pass B first-valid select -> shfl min-reduce.
__global__ __launch_bounds__(THREADS) void spiking_conv2d_kernel(
    const float* __restrict__ tj,        // [B,56,56,16]
    const float* __restrict__ kern,      // [3,3,16,16] flat [144*16]
    const float* __restrict__ threshold, // [16]
    const float* __restrict__ alpha,     // [16]
    float* __restrict__ out,             // [B,56,56,16]
    int npix)
{
    __shared__ float    sJ[KK * FT];            // 9216 B
    __shared__ uint64_t sKey[WAVES][KK + 2];    // 146 u64/wave (sentinel @144, pad), 4672 B

    const int tid  = threadIdx.x;
    const int wave = tid >> 6;
    const int lane = tid & 63;

    for (int i = tid; i < KK * FT; i += THREADS) sJ[i] = kern[i];
    __syncthreads();                            // the only barrier

    const int n = blockIdx.x * WAVES + wave;    // pixel id
    if (n >= npix) return;

    const int hw  = HT * WD;
    const int bb  = n / hw;
    const int rem = n - bb * hw;
    const int y   = rem / WD;
    const int x   = rem - y * WD;

    // ---------------- phase 1: build keys + rank sort --------------------------
    auto makeKey = [&](int k) -> uint64_t {
        const int tap = k >> 4;                 // di*3+dj
        const int ch  = k & 15;
        const int di  = tap / 3;
        const int dj  = tap - 3 * di;
        const int yy  = y + di - 1;             // 'same' pad
        const int xx  = x + dj - 1;
        float t = 0.0f;                         // T_MIN pad
        if ((unsigned)yy < (unsigned)HT && (unsigned)xx < (unsigned)WD)
            t = tj[(((bb * HT) + yy) * WD + xx) * CH + ch];
        // t >= 0 so unsigned bit order == float order; low 32 bits = stable tie-break
        return ((uint64_t)__float_as_uint(t) << 32) | (uint32_t)k;
    };

    const uint64_t key0 = makeKey(lane);
    const uint64_t key1 = makeKey(lane + 64);
    const uint64_t key2 = (lane < 16) ? makeKey(lane + 128) : ~0ull;

    sKey[wave][lane]      = key0;
    sKey[wave][lane + 64] = key1;
    if (lane < 16) sKey[wave][lane + 128] = key2;
    if (lane == 0) sKey[wave][KK] = ((uint64_t)0x49742400u) << 32;  // 1e6f sentinel

    int r0 = 0, r1 = 0, r2 = 0;
    {
        const ulonglong2* kp = (const ulonglong2*)(&sKey[wave][0]);
        #pragma unroll 4
        for (int j = 0; j < KK / 2; ++j) {
            const ulonglong2 kj = kp[j];        // broadcast b128 read
            r0 += (kj.x < key0) + (kj.y < key0);
            r1 += (kj.x < key1) + (kj.y < key1);
            r2 += (kj.x < key2) + (kj.y < key2);
        }
    }
    // scatter to sorted position, in place (register keys survive; same-wave LDS is in-order)
    sKey[wave][r0] = key0;
    sKey[wave][r1] = key1;
    if (lane < 16) sKey[wave][r2] = key2;

    // ---------------- phase 2: 16 features x 4 chunks --------------------------
    const int f    = lane & 15;
    const int c    = lane >> 4;
    const int kbeg = c * CHUNK;
    const float thr = threshold[f];
    const float al  = alpha[f];

    // pass A: per-chunk partial sums
    float lN = 0.0f, lD = 0.0f;
    #pragma unroll 4
    for (int i = 0; i < CHUNK; ++i) {
        const uint64_t e = sKey[wave][kbeg + i];
        const float t  = __uint_as_float((uint32_t)(e >> 32));
        const int   kj = (int)(uint32_t)e;
        const float w  = sJ[kj * FT + f];
        lN = fmaf(w, t, lN);
        lD += w;
    }
    // Hillis-Steele inclusive scan over chunks (lanes with same f), then exclusive
    float iN = lN, iD = lD;
    {
        float tN = __shfl_up(iN, 16), tD = __shfl_up(iD, 16);
        if (c >= 1) { iN += tN; iD += tD; }
        tN = __shfl_up(iN, 32); tD = __shfl_up(iD, 32);
        if (c >= 2) { iN += tN; iD += tD; }
    }
    float num = iN - lN;   // exclusive prefix of cumsum(J*t)
    float den = iD - lD;   // exclusive prefix of cumsum(J)

    // pass B: first valid candidate within chunk
    float selN = 0.0f, selD = 1.0f;
    bool  found = false;
    uint64_t ecur = sKey[wave][kbeg];
    #pragma unroll 4
    for (int i = 0; i < CHUNK; ++i) {
        const uint64_t enext = sKey[wave][kbeg + i + 1];
        const float t  = __uint_as_float((uint32_t)(ecur >> 32));
        const int   kj = (int)(uint32_t)ecur;
        const float tn = __uint_as_float((uint32_t)(enext >> 32));
        const float w  = sJ[kj * FT + f];
        num = fmaf(w, t, num);
        den += w;
        const float numt = num + thr;           // + alpha*T_MIN_PREV (=0)
        const float dena = den + al;
        // valid = (numt/dena < tn) && (dena > 0), division-free
        const bool valid = (dena > 0.0f) && (numt < tn * dena);
        const bool take  = !found && (valid || (c == 0 && i == 0));  // argmax fallback = k0
        if (take) { selN = numt; selD = dena; }
        found = found || valid;
        ecur = enext;
    }
    int pos = found ? c : ((c == 0) ? 6 : 7);   // 6 = chunk0 fallback sentinel

    // min-pos reduce across the 4 chunks of this feature
    {
        int   opos = __shfl_xor(pos, 16);
        float oN   = __shfl_xor(selN, 16);
        float oD   = __shfl_xor(selD, 16);
        if (opos < pos) { pos = opos; selN = oN; selD = oD; }
        opos = __shfl_xor(pos, 32);
        oN   = __shfl_xor(selN, 32);
        oD   = __shfl_xor(selD, 32);
        if (opos < pos) { pos = opos; selN = oN; selD = oD; }
    }
    if (c == 0) {
        const float ti = selN / selD;
        out[n * FT + f] = (ti < 1.0f) ? ti : 1.0f;   // clamp to T_MAX
    }
}

extern "C" void kernel_launch(void* const* d_in, const int* in_sizes, int n_in,
                              void* d_out, int out_size, void* d_ws, size_t ws_size,
                              hipStream_t stream) {
    const float* tj    = (const float*)d_in[0];
    const float* kern  = (const float*)d_in[1];
    const float* thr   = (const float*)d_in[2];
    const float* alpha = (const float*)d_in[3];
    float*       out   = (float*)d_out;

    const int npix   = in_sizes[0] / CH;                  // B*H*W = 12544
    const int blocks = (npix + WAVES - 1) / WAVES;        // 3136
    spiking_conv2d_kernel<<<blocks, THREADS, 0, stream>>>(tj, kern, thr, alpha, out, npix);
}